// Round 8
// baseline (161.363 us; speedup 1.0000x reference)
//
#include <hip/hip_runtime.h>

#define F_IN 256
#define F_OUT 64
#define BSH 7             // bin width 128 nodes (staging granularity)
#define BINW 128
#define NBINS_CAP 512     // LDS histogram capacity in bin_count (N <= 65536)
#define BATCH 2048        // edges per block in bin_count (8 per thread, R17)
#define CSTRIDE 16        // cursor padded to one 64B line per bin
#define MAXBIN_CAP 2560   // per-bin staging capacity
#define HCAP 1536         // half-bin CSR capacity (mean 1024, ~16 sd)

typedef __attribute__((ext_vector_type(8))) short short8;
typedef __attribute__((ext_vector_type(4))) float f32x4;

// ---------------------------------------------------------------------------
// bf16 helpers. Hot-path pack via HW v_cvt_pk_bf16_f32 (RNE, 2 floats/instr).
// ---------------------------------------------------------------------------
__device__ inline float bf_lo(unsigned u) { return __uint_as_float(u << 16); }
__device__ inline float bf_hi(unsigned u) { return __uint_as_float(u & 0xFFFF0000u); }
__device__ inline unsigned cvt_pk_bf16(float lo, float hi) {
    unsigned r;
    asm("v_cvt_pk_bf16_f32 %0, %1, %2" : "=v"(r) : "v"(lo), "v"(hi));
    return r;
}
__device__ inline short8 pack_cvt(float4 a, float4 b) {
    union { unsigned u[4]; short8 s; } r;
    r.u[0] = cvt_pk_bf16(a.x, a.y);
    r.u[1] = cvt_pk_bf16(a.z, a.w);
    r.u[2] = cvt_pk_bf16(b.x, b.y);
    r.u[3] = cvt_pk_bf16(b.z, b.w);
    return r.s;
}

// ---------------------------------------------------------------------------
// K1: bin edges by dst>>BSH into per-bin staging (packed u32: src | dstLow<<16,
// N <= 65536). R17: BATCH 2048 -> 391 blocks (~1.5/CU) vs 196 (<1/CU):
// cursor-line atomic depth 391 (padded lines, R9) traded for 2x occupancy.
// R15 rule honored: staging chunk writes are contiguous per (block,bin),
// ~2-3 block-writers per 64B line. R16 rule: LDS atomics index __shared__
// arrays directly (generic pointers emit flat atomics -> R6's 352us).
// ---------------------------------------------------------------------------
__global__ __launch_bounds__(256) void bin_count(const int* __restrict__ adj,
                                                 unsigned* __restrict__ staging,
                                                 int* __restrict__ cursor,
                                                 int E, int nbins, int maxBin) {
    __shared__ int cnt[NBINS_CAP];
    __shared__ int base[NBINS_CAP];
    const int tid = threadIdx.x;
    for (int i = tid; i < NBINS_CAP; i += 256) cnt[i] = 0;
    __syncthreads();

    const int e0 = blockIdx.x * BATCH + tid * 8;
    int S[8], D[8], sl[8];
    int nv = 0;
    if (e0 + 8 <= E) {
#pragma unroll
        for (int k = 0; k < 2; k++) {
            *(int4*)&S[k * 4] = *(const int4*)&adj[e0 + k * 4];
            *(int4*)&D[k * 4] = *(const int4*)&adj[E + e0 + k * 4];
        }
        nv = 8;
    } else if (e0 < E) {
        for (int k = 0; k < 8 && e0 + k < E; k++) {
            S[k] = adj[e0 + k];
            D[k] = adj[E + e0 + k];
            nv++;
        }
    }
#pragma unroll
    for (int j = 0; j < 8; j++) {
        if (j < nv) sl[j] = atomicAdd(&cnt[D[j] >> BSH], 1);
    }
    __syncthreads();
    for (int i = tid; i < nbins; i += 256) {
        int cv = cnt[i];
        base[i] = cv ? atomicAdd(&cursor[i * CSTRIDE], cv) : 0;
    }
    __syncthreads();
#pragma unroll
    for (int j = 0; j < 8; j++) {
        if (j < nv) {
            int b = D[j] >> BSH;
            int pos = base[b] + sl[j];
            if (pos < maxBin)
                staging[(size_t)b * maxBin + pos] =
                    (unsigned)S[j] | ((unsigned)(D[j] & (BINW - 1)) << 16);
        }
    }
}

// ---------------------------------------------------------------------------
// K2: fused [half-bin deg-hist -> dinv] + [g(bf16) = dinv*(x @ W) via MFMA].
// R17: 64 nodes/block, 782 blocks x 256 thr (4 waves) — fixes the 2:1 tail
// imbalance of 391-block launches (135 CUs got 2 blocks, 121 got 1) and
// raises co-resident waves for latency hiding. launch_bounds(256,4): VGPR
// cap 128 keeps the 16 hoisted x float4-loads in flight; LDS 32KB -> 4/CU.
// ---------------------------------------------------------------------------
__global__ __launch_bounds__(256, 4) void gemm_mfma(const float* __restrict__ x,
                                                    const float* __restrict__ W,
                                                    const unsigned* __restrict__ staging,
                                                    const int* __restrict__ cursor,
                                                    unsigned* __restrict__ gu,
                                                    int N, int maxBin) {
    __shared__ unsigned Wf[32 * 64 * 4];  // 32 KB: [kchunk][n][4 x u32(bf16x2)]
    __shared__ int degL[64];
    __shared__ float dinvL[64];
    const int b = blockIdx.x;         // half-bin id: bin = b>>1, half = b&1
    const int tid = threadIdx.x;

    if (tid < 64) degL[tid] = 0;
    for (int p = tid; p < (F_IN / 2) * F_OUT; p += 256) {
        int kp = p >> 6;
        int n = p & 63;
        int k = kp * 2;
        Wf[((k >> 3) * 64 + n) * 4 + ((k & 7) >> 1)] =
            cvt_pk_bf16(W[k * F_OUT + n], W[(k + 1) * F_OUT + n]);
    }
    __syncthreads();

    const int bin = b >> 1;
    const int half = b & 1;
    const int segCnt = min(cursor[bin * CSTRIDE], maxBin);
    const unsigned* seg = staging + (size_t)bin * maxBin;
    for (int i = tid; i < segCnt; i += 256) {
        int dl = seg[i] >> 16;
        if ((dl >> 6) == half) atomicAdd(&degL[dl & 63], 1);
    }
    __syncthreads();
    if (tid < 64) dinvL[tid] = rsqrtf((float)degL[tid] + 1.0f);
    __syncthreads();

    const int wave = tid >> 6;
    const int lane = tid & 63;
    const int q = lane >> 4;
    const int c = lane & 15;
    const int n0 = b * 64 + wave * 16;
    const int r = min(n0 + c, N - 1);
    const float* p0 = x + (size_t)r * F_IN + q * 8;

    f32x4 acc[4] = {};
#pragma unroll
    for (int s = 0; s < 8; s++) {
        float4 a0 = *(const float4*)(p0 + s * 32);
        float4 a1 = *(const float4*)(p0 + s * 32 + 4);
        short8 ah = pack_cvt(a0, a1);
#pragma unroll
        for (int t = 0; t < 4; t++) {
            short8 bh = *(const short8*)&Wf[((s * 4 + q) * 64 + t * 16 + c) * 4];
            acc[t] = __builtin_amdgcn_mfma_f32_16x16x32_bf16(ah, bh, acc[t], 0, 0, 0);
        }
    }

    // D layout: col = t*16 + c (feature), row = q*4 + rr (node). Pack col
    // pairs via shfl_xor(1), store bf16x2.
#pragma unroll
    for (int rr = 0; rr < 4; rr++) {
        int node = n0 + q * 4 + rr;
        float dv = dinvL[wave * 16 + q * 4 + rr];
#pragma unroll
        for (int t = 0; t < 4; t++) {
            float v = acc[t][rr] * dv;
            float o = __shfl_xor(v, 1, 64);
            if (node < N && !(lane & 1)) {
                gu[(size_t)node * 32 + t * 8 + (c >> 1)] = cvt_pk_bf16(v, o);
            }
        }
    }
}

// ---------------------------------------------------------------------------
// K3: gather via half-bin CSR in LDS. R17: one block per 64 nodes (782 x 256
// thr, ~3.6KB LDS -> high co-residency). (a) filter the bin's staged segment
// to this half, histogram + 1-wave scan + scatter into binCsr[1536] u16;
// (b) proven register-accumulate gather: wave = 16 nodes, 8 groups x 8
// lanes, one coalesced 128B g-row per edge, 2-deep unroll, shfl_xor reduce,
// fused self+dinv+bias+relu. dinv recomputed locally (rsqrtf(deg+1)).
// ---------------------------------------------------------------------------
__global__ __launch_bounds__(256, 4) void gather_bin(const unsigned* __restrict__ staging,
                                                     const int* __restrict__ cursor,
                                                     const unsigned* __restrict__ g32,
                                                     const float* __restrict__ bias,
                                                     float* __restrict__ out,
                                                     int N, int maxBin) {
    __shared__ int cnt[64];
    __shared__ int off[64];
    __shared__ unsigned short binCsr[HCAP];
    const int b = blockIdx.x;  // half-bin id
    const int tid = threadIdx.x;
    const int gn0 = b * 64;

    if (tid < 64) cnt[tid] = 0;
    __syncthreads();

    const int bin = b >> 1;
    const int half = b & 1;
    const int segCnt = min(cursor[bin * CSTRIDE], maxBin);
    const unsigned* seg = staging + (size_t)bin * maxBin;

    unsigned ev[10];
    int sl[10];
    int nv = 0;
#pragma unroll
    for (int r = 0; r < 10; r++) {
        int i = tid + r * 256;
        sl[r] = -1;
        if (i < segCnt) {
            unsigned e = seg[i];
            int dl = e >> 16;
            nv = r + 1;
            if ((dl >> 6) == half) {
                ev[r] = e;
                sl[r] = atomicAdd(&cnt[dl & 63], 1);
            }
        }
    }
    __syncthreads();

    if (tid < 64) {  // 1-wave exclusive scan of cnt[64]
        int v = cnt[tid];
        int incl = v;
        for (int d = 1; d < 64; d <<= 1) {
            int t = __shfl_up(incl, d, 64);
            if (tid >= d) incl += t;
        }
        off[tid] = incl - v;
    }
    __syncthreads();

#pragma unroll
    for (int r = 0; r < 10; r++) {
        if (r < nv && sl[r] >= 0) {
            int pos = off[(ev[r] >> 16) & 63] + sl[r];
            if (pos < HCAP) binCsr[pos] = (unsigned short)(ev[r] & 0xFFFFu);
        }
    }
    __syncthreads();

    const int wv = tid >> 6;
    const int lane = tid & 63;
    const int grp = lane >> 3;
    const int h = lane & 7;
    const uint4* g4 = (const uint4*)g32;

    for (int t = 0; t < 16; t++) {
        const int l = wv * 16 + t;
        const int gn = gn0 + l;
        if (gn >= N) break;
        const int start = off[l];
        const int deg = cnt[l];

        float a0[8] = {}, a1[8] = {};
        int i = grp;
        for (; i + 8 < deg; i += 16) {
            int s0 = binCsr[start + i], s1 = binCsr[start + i + 8];
            uint4 u0 = g4[(size_t)s0 * 8 + h];
            uint4 u1 = g4[(size_t)s1 * 8 + h];
            a0[0] += bf_lo(u0.x); a0[1] += bf_hi(u0.x);
            a0[2] += bf_lo(u0.y); a0[3] += bf_hi(u0.y);
            a0[4] += bf_lo(u0.z); a0[5] += bf_hi(u0.z);
            a0[6] += bf_lo(u0.w); a0[7] += bf_hi(u0.w);
            a1[0] += bf_lo(u1.x); a1[1] += bf_hi(u1.x);
            a1[2] += bf_lo(u1.y); a1[3] += bf_hi(u1.y);
            a1[4] += bf_lo(u1.z); a1[5] += bf_hi(u1.z);
            a1[6] += bf_lo(u1.w); a1[7] += bf_hi(u1.w);
        }
        if (i < deg) {
            int s0 = binCsr[start + i];
            uint4 u0 = g4[(size_t)s0 * 8 + h];
            a0[0] += bf_lo(u0.x); a0[1] += bf_hi(u0.x);
            a0[2] += bf_lo(u0.y); a0[3] += bf_hi(u0.y);
            a0[4] += bf_lo(u0.z); a0[5] += bf_hi(u0.z);
            a0[6] += bf_lo(u0.w); a0[7] += bf_hi(u0.w);
        }
        float acc[8];
#pragma unroll
        for (int k = 0; k < 8; k++) acc[k] = a0[k] + a1[k];
#pragma unroll
        for (int m = 8; m < 64; m <<= 1) {
#pragma unroll
            for (int k = 0; k < 8; k++) acc[k] += __shfl_xor(acc[k], m, 64);
        }
        if (grp == 0) {
            uint4 us = g4[(size_t)gn * 8 + h];  // self loop
            float dv = rsqrtf((float)deg + 1.0f);
            float s0 = bf_lo(us.x), s1 = bf_hi(us.x), s2 = bf_lo(us.y), s3 = bf_hi(us.y);
            float s4 = bf_lo(us.z), s5 = bf_hi(us.z), s6 = bf_lo(us.w), s7 = bf_hi(us.w);
            float4 b0 = *(const float4*)&bias[h * 8];
            float4 b1 = *(const float4*)&bias[h * 8 + 4];
            float4 r0, r1;
            r0.x = fmaxf(fmaf(dv, acc[0] + s0, b0.x), 0.0f);
            r0.y = fmaxf(fmaf(dv, acc[1] + s1, b0.y), 0.0f);
            r0.z = fmaxf(fmaf(dv, acc[2] + s2, b0.z), 0.0f);
            r0.w = fmaxf(fmaf(dv, acc[3] + s3, b0.w), 0.0f);
            r1.x = fmaxf(fmaf(dv, acc[4] + s4, b1.x), 0.0f);
            r1.y = fmaxf(fmaf(dv, acc[5] + s5, b1.y), 0.0f);
            r1.z = fmaxf(fmaf(dv, acc[6] + s6, b1.z), 0.0f);
            r1.w = fmaxf(fmaf(dv, acc[7] + s7, b1.w), 0.0f);
            *(float4*)&out[(size_t)gn * F_OUT + h * 8] = r0;
            *(float4*)&out[(size_t)gn * F_OUT + h * 8 + 4] = r1;
        }
    }
}

extern "C" void kernel_launch(void* const* d_in, const int* in_sizes, int n_in,
                              void* d_out, int out_size, void* d_ws, size_t ws_size,
                              hipStream_t stream) {
    const float* x = (const float*)d_in[0];
    const int* adj = (const int*)d_in[1];
    const float* W = (const float*)d_in[2];
    const float* b = (const float*)d_in[3];
    float* out = (float*)d_out;

    const int N = in_sizes[0] / F_IN;  // 50000 (u16 packing assumes N <= 65536)
    const int E = in_sizes[1] / 2;     // 800000
    const int nbins = (N + BINW - 1) >> BSH;  // 391 (<= NBINS_CAP)
    const int maxBin = MAXBIN_CAP;            // 2560, ~11 sd above mean 2047
    const int nhalf = (N + 63) / 64;          // 782 half-bins

    // ws: cursor(nbins*64B, zeroed) | staging(nbins*maxBin u32) | g16(N*32 u32)
    char* ws = (char*)d_ws;
    size_t segCur = (((size_t)nbins * CSTRIDE * 4) + 255) & ~(size_t)255;
    size_t segStg = (((size_t)nbins * maxBin * 4) + 255) & ~(size_t)255;
    int* cursor = (int*)ws;
    unsigned* staging = (unsigned*)(ws + segCur);
    unsigned* g16 = (unsigned*)(ws + segCur + segStg);

    hipMemsetAsync(cursor, 0, segCur, stream);

    bin_count<<<(E + BATCH - 1) / BATCH, 256, 0, stream>>>(adj, staging, cursor,
                                                           E, nbins, maxBin);
    gemm_mfma<<<nhalf, 256, 0, stream>>>(x, W, staging, cursor, g16, N, maxBin);
    gather_bin<<<nhalf, 256, 0, stream>>>(staging, cursor, g16, b, out, N, maxBin);
}